// Round 2
// baseline (395.500 us; speedup 1.0000x reference)
//
#include <hip/hip_runtime.h>
#include <hip/hip_fp16.h>
#include <cstdint>

#define DI __device__ __forceinline__

typedef _Float16 f16;
typedef _Float16 half8 __attribute__((ext_vector_type(8)));
typedef float f32x4 __attribute__((ext_vector_type(4)));

constexpr int NF  = 4096;   // features (in = out)
constexpr int TSZ = 512;    // crossbar tile size

// Match JAX f32 weak-typing: f64 python scalars cast to f32 at op time.
constexpr float G_MIN  = (float)(1.0 / 1.0e6);
constexpr float GRANGE = (float)(1.0e-4 - 1.0e-6);            // G_MAX - G_MIN
constexpr float QSTEP  = (float)((1.0e-4 - 1.0e-6) / 15.0);   // (G_MAX-G_MIN)/(2^4-1)

// ---------------- K0: x -> f16 ----------------
__global__ void convert_x(const float* __restrict__ x, f16* __restrict__ xh) {
    int idx = blockIdx.x * 256 + threadIdx.x;     // 1M float4
    float4 v = ((const float4*)x)[idx];
    union { f16 h[4]; uint2 u; } o;
    o.h[0] = (f16)v.x; o.h[1] = (f16)v.y; o.h[2] = (f16)v.z; o.h[3] = (f16)v.w;
    ((uint2*)xh)[idx] = o.u;
}

// ---------------- K1: per-tile min/max ----------------
__global__ void tile_minmax(const float* __restrict__ w,
                            float* __restrict__ wmin, float* __restrict__ wmax) {
    int tile = blockIdx.x; int it = tile >> 3, jt = tile & 7;
    const float* base = w + (size_t)it * TSZ * NF + jt * TSZ;
    float mn = 3.4e38f, mx = -3.4e38f;
    int t = threadIdx.x;
    for (int idx = t; idx < TSZ * (TSZ / 4); idx += 256) {
        int r = idx >> 7, c4 = idx & 127;
        float4 v = ((const float4*)(base + (size_t)r * NF))[c4];
        mn = fminf(mn, fminf(fminf(v.x, v.y), fminf(v.z, v.w)));
        mx = fmaxf(mx, fmaxf(fmaxf(v.x, v.y), fmaxf(v.z, v.w)));
    }
    for (int d = 1; d < 64; d <<= 1) {
        mn = fminf(mn, __shfl_xor(mn, d)); mx = fmaxf(mx, __shfl_xor(mx, d));
    }
    __shared__ float smn[4], smx[4];
    int wv = t >> 6;
    if ((t & 63) == 0) { smn[wv] = mn; smx[wv] = mx; }
    __syncthreads();
    if (t == 0) {
        wmin[tile] = fminf(fminf(smn[0], smn[1]), fminf(smn[2], smn[3]));
        wmax[tile] = fmaxf(fmaxf(smx[0], smx[1]), fmaxf(smx[2], smx[3]));
    }
}

// -------- K2: transform w -> wq_f16, H_f16 (transposed: [tile][n][k]) --------
// wq = dequantized weight (so x@wq == (ideal - offset)/s exactly, affine-inverted)
// H  = g_eff/s           (so x@H  == currents/s)
// Quantization arithmetic must match jnp bit-for-bit: unfused f32 mul/add, IEEE
// f32 divide, rintf (ties-to-even). fp contract OFF for this kernel.
__global__ void transform_w(const float* __restrict__ w,
                            const float* __restrict__ wmin_, const float* __restrict__ wmax_,
                            f16* __restrict__ wq_t, f16* __restrict__ h_t) {
#pragma clang fp contract(off)
    __shared__ f16 lwq[64][72];
    __shared__ f16 lh[64][72];
    int tile = blockIdx.x >> 6; int it = tile >> 3, jt = tile & 7;
    int sub = blockIdx.x & 63; int k0 = (sub >> 3) << 6, n0 = (sub & 7) << 6;
    float wmin = wmin_[tile], wmax = wmax_[tile];
    float s = GRANGE / (wmax - wmin + 1e-12f);
    float inv_s = 1.0f / s;
    int t = threadIdx.x, cn = t & 63, r0 = t >> 6;
    for (int rr = 0; rr < 16; ++rr) {
        int rk = rr * 4 + r0;     // local k in [0,64)
        float wv = w[(size_t)(it * TSZ + k0 + rk) * NF + jt * TSZ + n0 + cn];
        float cond  = (wv - wmin) * s + G_MIN;            // unfused, = reference
        float q     = rintf((cond - G_MIN) / QSTEP);      // ties-to-even, IEEE div
        float condq = q * QSTEP + G_MIN;                  // unfused, = reference
        float wqv   = (condq - G_MIN) * inv_s + wmin;     // our own math (any rounding)
        float rw    = 2.0f * ((512.0f - (float)(k0 + rk)) + ((float)(n0 + cn) + 1.0f));
        float ge    = 1.0f / (1.0f / condq + rw);         // IEEE f32 divs, = reference
        lwq[rk][cn] = (f16)wqv;
        lh[rk][cn]  = (f16)(ge * inv_s);
    }
    __syncthreads();
    // write transposed: [tile][n][k], k contiguous, vectorized by pairs of k
    for (int pp = 0; pp < 8; ++pp) {
        int nl = pp * 8 + (t >> 5);
        int kp = (t & 31) * 2;
        union { f16 h[2]; uint32_t u; } a, b;
        a.h[0] = lwq[kp][nl]; a.h[1] = lwq[kp + 1][nl];
        b.h[0] = lh[kp][nl];  b.h[1] = lh[kp + 1][nl];
        size_t obase = (size_t)tile * TSZ * TSZ + (size_t)(n0 + nl) * TSZ + k0 + kp;
        *(uint32_t*)(wq_t + obase) = a.u;
        *(uint32_t*)(h_t + obase)  = b.u;
    }
}

// ---------------- GEMM: per (tile, mb, nb): C[128x128] = x[128xK] @ B_t^T ----
DI void gl16(const void* g, void* l) {
    auto gp = reinterpret_cast<const uint32_t __attribute__((address_space(1)))*>(
        reinterpret_cast<uintptr_t>(g));
    auto lp = reinterpret_cast<uint32_t __attribute__((address_space(3)))*>(
        reinterpret_cast<uintptr_t>(l));
    __builtin_amdgcn_global_load_lds(gp, lp, 16, 0, 0);
}

// MODE 0: stats only (P pass).  MODE 1: store C as f16 + stats (Q pass).
template <int MODE>
__global__ __launch_bounds__(256, 2)
void gemm_tile(const f16* __restrict__ A, const f16* __restrict__ Bmat,
               f16* __restrict__ Cout, float* __restrict__ pmx,
               float* __restrict__ pmn, float* __restrict__ psm) {
    __shared__ __align__(16) f16 As[2][4096];   // [buf][128 rows][32 k], 16B-slot swizzle
    __shared__ __align__(16) f16 Bs[2][4096];
    __shared__ float sred[128][2][4];

    int bx = blockIdx.x;
    int tile = bx >> 5, mb = (bx >> 2) & 7, nb = bx & 3;
    int it = tile >> 3;
    int t = threadIdx.x, lane = t & 63, w = t >> 6;
    int wr = w >> 1, wc = w & 1;

    const f16* Ab = A + (size_t)(mb * 128) * NF + it * TSZ;
    const f16* Bb = Bmat + ((size_t)tile * TSZ + nb * 128) * TSZ;

    // staging: 512 16B chunks per matrix; thread stages chunks t and t+256.
    // chunk l -> LDS halfs [8l,8l+8) (wave-uniform base + lane*16B rule);
    // source k-slot pre-swizzled: slot -> k = (slot ^ ((row>>1)&3))*8
    int l1 = t, l2 = t + 256;
    int r1 = l1 >> 2, k1 = ((l1 & 3) ^ ((r1 >> 1) & 3)) * 8;
    int r2 = l2 >> 2, k2 = ((l2 & 3) ^ ((r2 >> 1) & 3)) * 8;
    const f16* a1 = Ab + (size_t)r1 * NF + k1;
    const f16* a2 = Ab + (size_t)r2 * NF + k2;
    const f16* b1 = Bb + (size_t)r1 * TSZ + k1;
    const f16* b2 = Bb + (size_t)r2 * TSZ + k2;

    f32x4 acc[4][4] = {};

    gl16(a1, &As[0][w * 512]); gl16(a2, &As[0][2048 + w * 512]);
    gl16(b1, &Bs[0][w * 512]); gl16(b2, &Bs[0][2048 + w * 512]);
    a1 += 32; a2 += 32; b1 += 32; b2 += 32;
    __syncthreads();

    int rA = wr * 64 + (lane & 15);
    int rB = wc * 64 + (lane & 15);
    int sl = lane >> 4;

    for (int kt = 0; kt < 16; ++kt) {
        int cur = kt & 1, nxt = cur ^ 1;
        if (kt < 15) {
            gl16(a1, &As[nxt][w * 512]); gl16(a2, &As[nxt][2048 + w * 512]);
            gl16(b1, &Bs[nxt][w * 512]); gl16(b2, &Bs[nxt][2048 + w * 512]);
            a1 += 32; a2 += 32; b1 += 32; b2 += 32;
        }
        half8 af[4], bf[4];
#pragma unroll
        for (int m = 0; m < 4; ++m) {
            int row = rA + m * 16;
            af[m] = *(const half8*)&As[cur][row * 32 + ((sl ^ ((row >> 1) & 3)) << 3)];
        }
#pragma unroll
        for (int n = 0; n < 4; ++n) {
            int row = rB + n * 16;
            bf[n] = *(const half8*)&Bs[cur][row * 32 + ((sl ^ ((row >> 1) & 3)) << 3)];
        }
#pragma unroll
        for (int m = 0; m < 4; ++m)
#pragma unroll
            for (int n = 0; n < 4; ++n)
                acc[m][n] = __builtin_amdgcn_mfma_f32_16x16x32_f16(af[m], bf[n], acc[m][n], 0, 0, 0);
        __syncthreads();
    }

    // ---- stats epilogue (both modes): per-row max/min/sum over this block's 128 cols
#pragma unroll
    for (int m = 0; m < 4; ++m) {
#pragma unroll
        for (int r = 0; r < 4; ++r) {
            float mx = -3.4e38f, mn = 3.4e38f, sm = 0.f;
#pragma unroll
            for (int n = 0; n < 4; ++n) {
                float v = acc[m][n][r];
                mx = fmaxf(mx, v); mn = fminf(mn, v); sm += v;
            }
#pragma unroll
            for (int d = 1; d < 16; d <<= 1) {
                mx = fmaxf(mx, __shfl_xor(mx, d));
                mn = fminf(mn, __shfl_xor(mn, d));
                sm += __shfl_xor(sm, d);
            }
            if ((lane & 15) == 0) {
                int row = wr * 64 + m * 16 + (lane >> 4) * 4 + r;
                sred[row][wc][0] = mx; sred[row][wc][1] = mn; sred[row][wc][2] = sm;
            }
        }
    }
    __syncthreads();
    if (t < 128) {
        float mx = fmaxf(sred[t][0][0], sred[t][1][0]);
        float mn = fminf(sred[t][0][1], sred[t][1][1]);
        float sm = sred[t][0][2] + sred[t][1][2];
        size_t idx = ((size_t)tile * 1024 + mb * 128 + t) * 4 + nb;
        pmx[idx] = mx; pmn[idx] = mn; psm[idx] = sm;
    }

    if (MODE == 1) {   // store C (f16)
        size_t base = ((size_t)tile * 1024 + mb * 128) * 512 + nb * 128;
#pragma unroll
        for (int m = 0; m < 4; ++m) {
            int row0 = wr * 64 + m * 16 + (lane >> 4) * 4;
#pragma unroll
            for (int n = 0; n < 4; ++n) {
                int col = wc * 64 + n * 16 + (lane & 15);
#pragma unroll
                for (int r = 0; r < 4; ++r)
                    Cout[base + (size_t)(row0 + r) * 512 + col] = (f16)acc[m][n][r];
            }
        }
    }
}

// ---------------- K5: fold partials -> per-(tile,row) alpha/beta ----------------
__global__ void alphabeta(const float* __restrict__ pmx, const float* __restrict__ pmn,
                          const float* __restrict__ psm,
                          const float* __restrict__ qmx, const float* __restrict__ qmn,
                          const float* __restrict__ qsm,
                          const float* __restrict__ wmin_, const float* __restrict__ wmax_,
                          float* __restrict__ alpha, float* __restrict__ beta) {
    int i = blockIdx.x * 256 + threadIdx.x;          // 64 tiles * 1024 rows
    int tile = i >> 10;
    float s = GRANGE / (wmax_[tile] - wmin_[tile] + 1e-12f);
    size_t p = (size_t)i * 4;
    float pmax = fmaxf(fmaxf(pmx[p], pmx[p+1]), fmaxf(pmx[p+2], pmx[p+3]));
    float pmin = fminf(fminf(pmn[p], pmn[p+1]), fminf(pmn[p+2], pmn[p+3]));
    float psum = psm[p] + psm[p+1] + psm[p+2] + psm[p+3];
    float qmax = fmaxf(fmaxf(qmx[p], qmx[p+1]), fmaxf(qmx[p+2], qmx[p+3]));
    float qmin = fminf(fminf(qmn[p], qmn[p+1]), fminf(qmn[p+2], qmn[p+3]));
    float qsum = qsm[p] + qsm[p+1] + qsm[p+2] + qsm[p+3];
    // coeff = (ideal.max-ideal.min)/(cur.max-cur.min+1e-8) with ideal=s*P+off, cur=s*Q
    float coeff = (s * (pmax - pmin)) / (s * (qmax - qmin) + 1e-8f);
    float meanP = psum * (1.0f / 512.0f);
    float meanQ = qsum * (1.0f / 512.0f);
    alpha[i] = coeff;
    beta[i]  = meanP - coeff * meanQ;    // out_tile = alpha*Q + beta  (per row)
}

// ---------------- K6: streaming combine ----------------
__global__ __launch_bounds__(256)
void combine(const f16* __restrict__ Q,
             const float* __restrict__ alpha, const float* __restrict__ beta,
             const float* __restrict__ bias, float* __restrict__ out) {
    int bid = blockIdx.x;
    int jt = bid & 7, b = bid >> 3;
    int t = threadIdx.x;
    float o0 = 0.f, o1 = 0.f, bsum = 0.f;
#pragma unroll
    for (int i = 0; i < 8; ++i) {
        int tile = i * 8 + jt;                        // block-uniform -> s_load
        int ab = tile * 1024 + b;
        float a = alpha[ab];
        bsum += beta[ab];
        union { uint32_t u; f16 h[2]; } q2;
        q2.u = ((const uint32_t*)(Q + ((size_t)tile * 1024 + b) * 512))[t];
        o0 = fmaf(a, (float)q2.h[0], o0);
        o1 = fmaf(a, (float)q2.h[1], o1);
    }
    float2 bv = ((const float2*)(bias + jt * 512))[t];
    float2 ov; ov.x = o0 + bsum + bv.x; ov.y = o1 + bsum + bv.y;
    ((float2*)(out + (size_t)b * 4096))[jt * 256 + t] = ov;
}

extern "C" void kernel_launch(void* const* d_in, const int* in_sizes, int n_in,
                              void* d_out, int out_size, void* d_ws, size_t ws_size,
                              hipStream_t stream) {
    const float* x    = (const float*)d_in[0];
    const float* wt   = (const float*)d_in[1];
    const float* bias = (const float*)d_in[2];
    float* out = (float*)d_out;
    char* ws = (char*)d_ws;

    float* wmin = (float*)ws;              // 64 f32
    float* wmax = (float*)(ws + 256);      // 64 f32
    size_t off = 1024;
    f16* xh   = (f16*)(ws + off); off += (size_t)1024 * 4096 * 2;       //   8 MB
    f16* wq_t = (f16*)(ws + off); off += (size_t)4096 * 4096 * 2;       //  32 MB
    f16* h_t  = (f16*)(ws + off); off += (size_t)4096 * 4096 * 2;       //  32 MB
    float* pmx = (float*)(ws + off); off += (size_t)64 * 1024 * 4 * 4;  //   1 MB
    float* pmn = (float*)(ws + off); off += (size_t)64 * 1024 * 4 * 4;
    float* psm = (float*)(ws + off); off += (size_t)64 * 1024 * 4 * 4;
    float* qmx = (float*)(ws + off); off += (size_t)64 * 1024 * 4 * 4;
    float* qmn = (float*)(ws + off); off += (size_t)64 * 1024 * 4 * 4;
    float* qsm = (float*)(ws + off); off += (size_t)64 * 1024 * 4 * 4;
    float* alpha = (float*)(ws + off); off += (size_t)64 * 1024 * 4;    // 256 KB
    float* beta  = (float*)(ws + off); off += (size_t)64 * 1024 * 4;
    f16* Q    = (f16*)(ws + off);                                       //  64 MB

    convert_x  <<<4096, 256, 0, stream>>>(x, xh);
    tile_minmax<<<64,   256, 0, stream>>>(wt, wmin, wmax);
    transform_w<<<4096, 256, 0, stream>>>(wt, wmin, wmax, wq_t, h_t);
    gemm_tile<0><<<2048, 256, 0, stream>>>(xh, wq_t, nullptr, pmx, pmn, psm);
    gemm_tile<1><<<2048, 256, 0, stream>>>(xh, h_t, Q, qmx, qmn, qsm);
    alphabeta  <<<256,  256, 0, stream>>>(pmx, pmn, psm, qmx, qmn, qsm,
                                          wmin, wmax, alpha, beta);
    combine    <<<8192, 256, 0, stream>>>(Q, alpha, beta, bias, out);
}

// Round 3
// 292.729 us; speedup vs baseline: 1.3511x; 1.3511x over previous
//
#include <hip/hip_runtime.h>
#include <hip/hip_fp16.h>
#include <cstdint>

#define DI __device__ __forceinline__

typedef _Float16 f16;
typedef _Float16 half8 __attribute__((ext_vector_type(8)));
typedef float f32x4 __attribute__((ext_vector_type(4)));

constexpr int NF  = 4096;   // features (in = out)
constexpr int TSZ = 512;    // crossbar tile size

// Match JAX f32 weak-typing: f64 python scalars cast to f32 at op time.
constexpr float G_MIN  = (float)(1.0 / 1.0e6);
constexpr float GRANGE = (float)(1.0e-4 - 1.0e-6);            // G_MAX - G_MIN
constexpr float QSTEP  = (float)((1.0e-4 - 1.0e-6) / 15.0);   // (G_MAX-G_MIN)/(2^4-1)

// ---------------- K0: x -> f16 ----------------
__global__ void convert_x(const float* __restrict__ x, f16* __restrict__ xh) {
    int idx = blockIdx.x * 256 + threadIdx.x;     // 1M float4
    float4 v = ((const float4*)x)[idx];
    union { f16 h[4]; uint2 u; } o;
    o.h[0] = (f16)v.x; o.h[1] = (f16)v.y; o.h[2] = (f16)v.z; o.h[3] = (f16)v.w;
    ((uint2*)xh)[idx] = o.u;
}

// ---------------- K1a: per-(tile, 32-row chunk) min/max partials ----------------
// grid = 64 tiles * 16 chunks = 1024 blocks; each block reads 32x512 f32 (64 KB).
__global__ __launch_bounds__(256)
void tile_minmax1(const float* __restrict__ w,
                  float* __restrict__ pmin, float* __restrict__ pmax) {
    int bid = blockIdx.x;
    int tile = bid >> 4, sub = bid & 15;
    int it = tile >> 3, jt = tile & 7;
    const float* base = w + (size_t)(it * TSZ + sub * 32) * NF + jt * TSZ;
    float mn = 3.4e38f, mx = -3.4e38f;
    int t = threadIdx.x;
#pragma unroll
    for (int i = 0; i < 16; ++i) {
        int idx = i * 256 + t;              // 0..4095
        int r = idx >> 7, c4 = idx & 127;   // 32 rows x 128 float4
        float4 v = ((const float4*)(base + (size_t)r * NF))[c4];
        mn = fminf(mn, fminf(fminf(v.x, v.y), fminf(v.z, v.w)));
        mx = fmaxf(mx, fmaxf(fmaxf(v.x, v.y), fmaxf(v.z, v.w)));
    }
    for (int d = 1; d < 64; d <<= 1) {
        mn = fminf(mn, __shfl_xor(mn, d)); mx = fmaxf(mx, __shfl_xor(mx, d));
    }
    __shared__ float smn[4], smx[4];
    int wv = t >> 6;
    if ((t & 63) == 0) { smn[wv] = mn; smx[wv] = mx; }
    __syncthreads();
    if (t == 0) {
        pmin[bid] = fminf(fminf(smn[0], smn[1]), fminf(smn[2], smn[3]));
        pmax[bid] = fmaxf(fmaxf(smx[0], smx[1]), fmaxf(smx[2], smx[3]));
    }
}

// ---------------- K1b: fold 16 partials/tile -> wmin/wmax[64] ----------------
// one block of 1024 threads; 16-lane shfl groups (tile = t>>4 contiguous in wave).
__global__ __launch_bounds__(1024)
void tile_minmax2(const float* __restrict__ pmin, const float* __restrict__ pmax,
                  float* __restrict__ wmin, float* __restrict__ wmax) {
    int t = threadIdx.x;
    float mn = pmin[t], mx = pmax[t];
#pragma unroll
    for (int d = 1; d < 16; d <<= 1) {
        mn = fminf(mn, __shfl_xor(mn, d));
        mx = fmaxf(mx, __shfl_xor(mx, d));
    }
    if ((t & 15) == 0) { wmin[t >> 4] = mn; wmax[t >> 4] = mx; }
}

// -------- K2: transform w -> wq_f16, H_f16 (transposed: [tile][n][k]) --------
// wq = dequantized weight (so x@wq == (ideal - offset)/s exactly, affine-inverted)
// H  = g_eff/s           (so x@H  == currents/s)
// Quantization arithmetic must match jnp bit-for-bit: unfused f32 mul/add, IEEE
// f32 divide, rintf (ties-to-even). fp contract OFF for this kernel.
__global__ void transform_w(const float* __restrict__ w,
                            const float* __restrict__ wmin_, const float* __restrict__ wmax_,
                            f16* __restrict__ wq_t, f16* __restrict__ h_t) {
#pragma clang fp contract(off)
    __shared__ f16 lwq[64][72];
    __shared__ f16 lh[64][72];
    int tile = blockIdx.x >> 6; int it = tile >> 3, jt = tile & 7;
    int sub = blockIdx.x & 63; int k0 = (sub >> 3) << 6, n0 = (sub & 7) << 6;
    float wmin = wmin_[tile], wmax = wmax_[tile];
    float s = GRANGE / (wmax - wmin + 1e-12f);
    float inv_s = 1.0f / s;
    int t = threadIdx.x, cn = t & 63, r0 = t >> 6;
    for (int rr = 0; rr < 16; ++rr) {
        int rk = rr * 4 + r0;     // local k in [0,64)
        float wv = w[(size_t)(it * TSZ + k0 + rk) * NF + jt * TSZ + n0 + cn];
        float cond  = (wv - wmin) * s + G_MIN;            // unfused, = reference
        float q     = rintf((cond - G_MIN) / QSTEP);      // ties-to-even, IEEE div
        float condq = q * QSTEP + G_MIN;                  // unfused, = reference
        float wqv   = (condq - G_MIN) * inv_s + wmin;     // our own math (any rounding)
        float rw    = 2.0f * ((512.0f - (float)(k0 + rk)) + ((float)(n0 + cn) + 1.0f));
        float ge    = 1.0f / (1.0f / condq + rw);         // IEEE f32 divs, = reference
        lwq[rk][cn] = (f16)wqv;
        lh[rk][cn]  = (f16)(ge * inv_s);
    }
    __syncthreads();
    // write transposed: [tile][n][k], k contiguous, vectorized by pairs of k
    for (int pp = 0; pp < 8; ++pp) {
        int nl = pp * 8 + (t >> 5);
        int kp = (t & 31) * 2;
        union { f16 h[2]; uint32_t u; } a, b;
        a.h[0] = lwq[kp][nl]; a.h[1] = lwq[kp + 1][nl];
        b.h[0] = lh[kp][nl];  b.h[1] = lh[kp + 1][nl];
        size_t obase = (size_t)tile * TSZ * TSZ + (size_t)(n0 + nl) * TSZ + k0 + kp;
        *(uint32_t*)(wq_t + obase) = a.u;
        *(uint32_t*)(h_t + obase)  = b.u;
    }
}

// ---------------- GEMM: per (tile, mb, nb): C[128x128] = x[128xK] @ B_t^T ----
DI void gl16(const void* g, void* l) {
    auto gp = reinterpret_cast<const uint32_t __attribute__((address_space(1)))*>(
        reinterpret_cast<uintptr_t>(g));
    auto lp = reinterpret_cast<uint32_t __attribute__((address_space(3)))*>(
        reinterpret_cast<uintptr_t>(l));
    __builtin_amdgcn_global_load_lds(gp, lp, 16, 0, 0);
}

// MODE 0: stats only (P pass).  MODE 1: store C as f16 + stats (Q pass).
template <int MODE>
__global__ __launch_bounds__(256, 2)
void gemm_tile(const f16* __restrict__ A, const f16* __restrict__ Bmat,
               f16* __restrict__ Cout, float* __restrict__ pmx,
               float* __restrict__ pmn, float* __restrict__ psm) {
    __shared__ __align__(16) f16 As[2][4096];   // [buf][128 rows][32 k], 16B-slot swizzle
    __shared__ __align__(16) f16 Bs[2][4096];
    __shared__ float sred[128][2][4];

    int bx = blockIdx.x;
    int tile = bx >> 5, mb = (bx >> 2) & 7, nb = bx & 3;
    int it = tile >> 3;
    int t = threadIdx.x, lane = t & 63, w = t >> 6;
    int wr = w >> 1, wc = w & 1;

    const f16* Ab = A + (size_t)(mb * 128) * NF + it * TSZ;
    const f16* Bb = Bmat + ((size_t)tile * TSZ + nb * 128) * TSZ;

    // staging: 512 16B chunks per matrix; thread stages chunks t and t+256.
    // chunk l -> LDS halfs [8l,8l+8) (wave-uniform base + lane*16B rule);
    // source k-slot pre-swizzled: slot -> k = (slot ^ ((row>>1)&3))*8
    int l1 = t, l2 = t + 256;
    int r1 = l1 >> 2, k1 = ((l1 & 3) ^ ((r1 >> 1) & 3)) * 8;
    int r2 = l2 >> 2, k2 = ((l2 & 3) ^ ((r2 >> 1) & 3)) * 8;
    const f16* a1 = Ab + (size_t)r1 * NF + k1;
    const f16* a2 = Ab + (size_t)r2 * NF + k2;
    const f16* b1 = Bb + (size_t)r1 * TSZ + k1;
    const f16* b2 = Bb + (size_t)r2 * TSZ + k2;

    f32x4 acc[4][4] = {};

    gl16(a1, &As[0][w * 512]); gl16(a2, &As[0][2048 + w * 512]);
    gl16(b1, &Bs[0][w * 512]); gl16(b2, &Bs[0][2048 + w * 512]);
    a1 += 32; a2 += 32; b1 += 32; b2 += 32;
    __syncthreads();

    int rA = wr * 64 + (lane & 15);
    int rB = wc * 64 + (lane & 15);
    int sl = lane >> 4;

    for (int kt = 0; kt < 16; ++kt) {
        int cur = kt & 1, nxt = cur ^ 1;
        if (kt < 15) {
            gl16(a1, &As[nxt][w * 512]); gl16(a2, &As[nxt][2048 + w * 512]);
            gl16(b1, &Bs[nxt][w * 512]); gl16(b2, &Bs[nxt][2048 + w * 512]);
            a1 += 32; a2 += 32; b1 += 32; b2 += 32;
        }
        half8 af[4], bf[4];
#pragma unroll
        for (int m = 0; m < 4; ++m) {
            int row = rA + m * 16;
            af[m] = *(const half8*)&As[cur][row * 32 + ((sl ^ ((row >> 1) & 3)) << 3)];
        }
#pragma unroll
        for (int n = 0; n < 4; ++n) {
            int row = rB + n * 16;
            bf[n] = *(const half8*)&Bs[cur][row * 32 + ((sl ^ ((row >> 1) & 3)) << 3)];
        }
#pragma unroll
        for (int m = 0; m < 4; ++m)
#pragma unroll
            for (int n = 0; n < 4; ++n)
                acc[m][n] = __builtin_amdgcn_mfma_f32_16x16x32_f16(af[m], bf[n], acc[m][n], 0, 0, 0);
        __syncthreads();
    }

    // ---- stats epilogue (both modes): per-row max/min/sum over this block's 128 cols
#pragma unroll
    for (int m = 0; m < 4; ++m) {
#pragma unroll
        for (int r = 0; r < 4; ++r) {
            float mx = -3.4e38f, mn = 3.4e38f, sm = 0.f;
#pragma unroll
            for (int n = 0; n < 4; ++n) {
                float v = acc[m][n][r];
                mx = fmaxf(mx, v); mn = fminf(mn, v); sm += v;
            }
#pragma unroll
            for (int d = 1; d < 16; d <<= 1) {
                mx = fmaxf(mx, __shfl_xor(mx, d));
                mn = fminf(mn, __shfl_xor(mn, d));
                sm += __shfl_xor(sm, d);
            }
            if ((lane & 15) == 0) {
                int row = wr * 64 + m * 16 + (lane >> 4) * 4 + r;
                sred[row][wc][0] = mx; sred[row][wc][1] = mn; sred[row][wc][2] = sm;
            }
        }
    }
    __syncthreads();
    if (t < 128) {
        float mx = fmaxf(sred[t][0][0], sred[t][1][0]);
        float mn = fminf(sred[t][0][1], sred[t][1][1]);
        float sm = sred[t][0][2] + sred[t][1][2];
        size_t idx = ((size_t)tile * 1024 + mb * 128 + t) * 4 + nb;
        pmx[idx] = mx; pmn[idx] = mn; psm[idx] = sm;
    }

    if (MODE == 1) {   // store C (f16)
        size_t base = ((size_t)tile * 1024 + mb * 128) * 512 + nb * 128;
#pragma unroll
        for (int m = 0; m < 4; ++m) {
            int row0 = wr * 64 + m * 16 + (lane >> 4) * 4;
#pragma unroll
            for (int n = 0; n < 4; ++n) {
                int col = wc * 64 + n * 16 + (lane & 15);
#pragma unroll
                for (int r = 0; r < 4; ++r)
                    Cout[base + (size_t)(row0 + r) * 512 + col] = (f16)acc[m][n][r];
            }
        }
    }
}

// ---------------- K5: fold partials -> per-(tile,row) alpha/beta ----------------
__global__ void alphabeta(const float* __restrict__ pmx, const float* __restrict__ pmn,
                          const float* __restrict__ psm,
                          const float* __restrict__ qmx, const float* __restrict__ qmn,
                          const float* __restrict__ qsm,
                          const float* __restrict__ wmin_, const float* __restrict__ wmax_,
                          float* __restrict__ alpha, float* __restrict__ beta) {
    int i = blockIdx.x * 256 + threadIdx.x;          // 64 tiles * 1024 rows
    int tile = i >> 10;
    float s = GRANGE / (wmax_[tile] - wmin_[tile] + 1e-12f);
    size_t p = (size_t)i * 4;
    float pmax = fmaxf(fmaxf(pmx[p], pmx[p+1]), fmaxf(pmx[p+2], pmx[p+3]));
    float pmin = fminf(fminf(pmn[p], pmn[p+1]), fminf(pmn[p+2], pmn[p+3]));
    float psum = psm[p] + psm[p+1] + psm[p+2] + psm[p+3];
    float qmax = fmaxf(fmaxf(qmx[p], qmx[p+1]), fmaxf(qmx[p+2], qmx[p+3]));
    float qmin = fminf(fminf(qmn[p], qmn[p+1]), fminf(qmn[p+2], qmn[p+3]));
    float qsum = qsm[p] + qsm[p+1] + qsm[p+2] + qsm[p+3];
    // coeff = (ideal.max-ideal.min)/(cur.max-cur.min+1e-8) with ideal=s*P+off, cur=s*Q
    float coeff = (s * (pmax - pmin)) / (s * (qmax - qmin) + 1e-8f);
    float meanP = psum * (1.0f / 512.0f);
    float meanQ = qsum * (1.0f / 512.0f);
    alpha[i] = coeff;
    beta[i]  = meanP - coeff * meanQ;    // out_tile = alpha*Q + beta  (per row)
}

// ---------------- K6: streaming combine ----------------
__global__ __launch_bounds__(256)
void combine(const f16* __restrict__ Q,
             const float* __restrict__ alpha, const float* __restrict__ beta,
             const float* __restrict__ bias, float* __restrict__ out) {
    int bid = blockIdx.x;
    int jt = bid & 7, b = bid >> 3;
    int t = threadIdx.x;
    float o0 = 0.f, o1 = 0.f, bsum = 0.f;
#pragma unroll
    for (int i = 0; i < 8; ++i) {
        int tile = i * 8 + jt;                        // block-uniform -> s_load
        int ab = tile * 1024 + b;
        float a = alpha[ab];
        bsum += beta[ab];
        union { uint32_t u; f16 h[2]; } q2;
        q2.u = ((const uint32_t*)(Q + ((size_t)tile * 1024 + b) * 512))[t];
        o0 = fmaf(a, (float)q2.h[0], o0);
        o1 = fmaf(a, (float)q2.h[1], o1);
    }
    float2 bv = ((const float2*)(bias + jt * 512))[t];
    float2 ov; ov.x = o0 + bsum + bv.x; ov.y = o1 + bsum + bv.y;
    ((float2*)(out + (size_t)b * 4096))[jt * 256 + t] = ov;
}

extern "C" void kernel_launch(void* const* d_in, const int* in_sizes, int n_in,
                              void* d_out, int out_size, void* d_ws, size_t ws_size,
                              hipStream_t stream) {
    const float* x    = (const float*)d_in[0];
    const float* wt   = (const float*)d_in[1];
    const float* bias = (const float*)d_in[2];
    float* out = (float*)d_out;
    char* ws = (char*)d_ws;

    float* wmin = (float*)ws;                  // 64 f32
    float* wmax = (float*)(ws + 256);          // 64 f32
    float* pmin1 = (float*)(ws + 512);         // 1024 f32 stage-1 partials
    float* pmax1 = (float*)(ws + 512 + 4096);  // 1024 f32
    size_t off = 512 + 8192;
    f16* xh   = (f16*)(ws + off); off += (size_t)1024 * 4096 * 2;       //   8 MB
    f16* wq_t = (f16*)(ws + off); off += (size_t)4096 * 4096 * 2;       //  32 MB
    f16* h_t  = (f16*)(ws + off); off += (size_t)4096 * 4096 * 2;       //  32 MB
    float* pmx = (float*)(ws + off); off += (size_t)64 * 1024 * 4 * 4;  //   1 MB
    float* pmn = (float*)(ws + off); off += (size_t)64 * 1024 * 4 * 4;
    float* psm = (float*)(ws + off); off += (size_t)64 * 1024 * 4 * 4;
    float* qmx = (float*)(ws + off); off += (size_t)64 * 1024 * 4 * 4;
    float* qmn = (float*)(ws + off); off += (size_t)64 * 1024 * 4 * 4;
    float* qsm = (float*)(ws + off); off += (size_t)64 * 1024 * 4 * 4;
    float* alpha = (float*)(ws + off); off += (size_t)64 * 1024 * 4;    // 256 KB
    float* beta  = (float*)(ws + off); off += (size_t)64 * 1024 * 4;
    f16* Q    = (f16*)(ws + off);                                       //  64 MB

    convert_x   <<<4096, 256,  0, stream>>>(x, xh);
    tile_minmax1<<<1024, 256,  0, stream>>>(wt, pmin1, pmax1);
    tile_minmax2<<<1,    1024, 0, stream>>>(pmin1, pmax1, wmin, wmax);
    transform_w <<<4096, 256,  0, stream>>>(wt, wmin, wmax, wq_t, h_t);
    gemm_tile<0><<<2048, 256,  0, stream>>>(xh, wq_t, nullptr, pmx, pmn, psm);
    gemm_tile<1><<<2048, 256,  0, stream>>>(xh, h_t, Q, qmx, qmn, qsm);
    alphabeta   <<<256,  256,  0, stream>>>(pmx, pmn, psm, qmx, qmn, qsm,
                                            wmin, wmax, alpha, beta);
    combine     <<<8192, 256,  0, stream>>>(Q, alpha, beta, bias, out);
}

// Round 4
// 285.620 us; speedup vs baseline: 1.3847x; 1.0249x over previous
//
#include <hip/hip_runtime.h>
#include <hip/hip_fp16.h>
#include <cstdint>

#define DI __device__ __forceinline__

typedef _Float16 f16;
typedef _Float16 half8 __attribute__((ext_vector_type(8)));
typedef float f32x4 __attribute__((ext_vector_type(4)));

constexpr int NF  = 4096;   // features (in = out)
constexpr int TSZ = 512;    // crossbar tile size

// Match JAX f32 weak-typing: f64 python scalars cast to f32 at op time.
constexpr float G_MIN  = (float)(1.0 / 1.0e6);
constexpr float GRANGE = (float)(1.0e-4 - 1.0e-6);            // G_MAX - G_MIN
constexpr float QSTEP  = (float)((1.0e-4 - 1.0e-6) / 15.0);   // (G_MAX-G_MIN)/(2^4-1)

// ---------------- K0: x -> f16 ----------------
__global__ void convert_x(const float* __restrict__ x, f16* __restrict__ xh) {
    int idx = blockIdx.x * 256 + threadIdx.x;     // 1M float4
    float4 v = ((const float4*)x)[idx];
    union { f16 h[4]; uint2 u; } o;
    o.h[0] = (f16)v.x; o.h[1] = (f16)v.y; o.h[2] = (f16)v.z; o.h[3] = (f16)v.w;
    ((uint2*)xh)[idx] = o.u;
}

// ---------------- K1a: per-(tile, 32-row chunk) min/max partials ----------------
__global__ __launch_bounds__(256)
void tile_minmax1(const float* __restrict__ w,
                  float* __restrict__ pmin, float* __restrict__ pmax) {
    int bid = blockIdx.x;
    int tile = bid >> 4, sub = bid & 15;
    int it = tile >> 3, jt = tile & 7;
    const float* base = w + (size_t)(it * TSZ + sub * 32) * NF + jt * TSZ;
    float mn = 3.4e38f, mx = -3.4e38f;
    int t = threadIdx.x;
#pragma unroll
    for (int i = 0; i < 16; ++i) {
        int idx = i * 256 + t;              // 0..4095
        int r = idx >> 7, c4 = idx & 127;   // 32 rows x 128 float4
        float4 v = ((const float4*)(base + (size_t)r * NF))[c4];
        mn = fminf(mn, fminf(fminf(v.x, v.y), fminf(v.z, v.w)));
        mx = fmaxf(mx, fmaxf(fmaxf(v.x, v.y), fmaxf(v.z, v.w)));
    }
    for (int d = 1; d < 64; d <<= 1) {
        mn = fminf(mn, __shfl_xor(mn, d)); mx = fmaxf(mx, __shfl_xor(mx, d));
    }
    __shared__ float smn[4], smx[4];
    int wv = t >> 6;
    if ((t & 63) == 0) { smn[wv] = mn; smx[wv] = mx; }
    __syncthreads();
    if (t == 0) {
        pmin[bid] = fminf(fminf(smn[0], smn[1]), fminf(smn[2], smn[3]));
        pmax[bid] = fmaxf(fmaxf(smx[0], smx[1]), fmaxf(smx[2], smx[3]));
    }
}

// ---------------- K1b: fold 16 partials/tile -> wmin/wmax[64] ----------------
__global__ __launch_bounds__(1024)
void tile_minmax2(const float* __restrict__ pmin, const float* __restrict__ pmax,
                  float* __restrict__ wmin, float* __restrict__ wmax) {
    int t = threadIdx.x;
    float mn = pmin[t], mx = pmax[t];
#pragma unroll
    for (int d = 1; d < 16; d <<= 1) {
        mn = fminf(mn, __shfl_xor(mn, d));
        mx = fmaxf(mx, __shfl_xor(mx, d));
    }
    if ((t & 15) == 0) { wmin[t >> 4] = mn; wmax[t >> 4] = mx; }
}

// -------- K2: transform w -> wq_f16, H_f16 (transposed: [tile][n][k]) --------
// Quantization arithmetic must match jnp bit-for-bit: unfused f32 mul/add, IEEE
// f32 divide, rintf (ties-to-even). fp contract OFF for this kernel.
__global__ void transform_w(const float* __restrict__ w,
                            const float* __restrict__ wmin_, const float* __restrict__ wmax_,
                            f16* __restrict__ wq_t, f16* __restrict__ h_t) {
#pragma clang fp contract(off)
    __shared__ f16 lwq[64][72];
    __shared__ f16 lh[64][72];
    int tile = blockIdx.x >> 6; int it = tile >> 3, jt = tile & 7;
    int sub = blockIdx.x & 63; int k0 = (sub >> 3) << 6, n0 = (sub & 7) << 6;
    float wmin = wmin_[tile], wmax = wmax_[tile];
    float s = GRANGE / (wmax - wmin + 1e-12f);
    float inv_s = 1.0f / s;
    int t = threadIdx.x, cn = t & 63, r0 = t >> 6;
    for (int rr = 0; rr < 16; ++rr) {
        int rk = rr * 4 + r0;     // local k in [0,64)
        float wv = w[(size_t)(it * TSZ + k0 + rk) * NF + jt * TSZ + n0 + cn];
        float cond  = (wv - wmin) * s + G_MIN;            // unfused, = reference
        float q     = rintf((cond - G_MIN) / QSTEP);      // ties-to-even, IEEE div
        float condq = q * QSTEP + G_MIN;                  // unfused, = reference
        float wqv   = (condq - G_MIN) * inv_s + wmin;     // our own math (any rounding)
        float rw    = 2.0f * ((512.0f - (float)(k0 + rk)) + ((float)(n0 + cn) + 1.0f));
        float ge    = 1.0f / (1.0f / condq + rw);         // IEEE f32 divs, = reference
        lwq[rk][cn] = (f16)wqv;
        lh[rk][cn]  = (f16)(ge * inv_s);
    }
    __syncthreads();
    // write transposed: [tile][n][k], k contiguous, vectorized by pairs of k
    for (int pp = 0; pp < 8; ++pp) {
        int nl = pp * 8 + (t >> 5);
        int kp = (t & 31) * 2;
        union { f16 h[2]; uint32_t u; } a, b;
        a.h[0] = lwq[kp][nl]; a.h[1] = lwq[kp + 1][nl];
        b.h[0] = lh[kp][nl];  b.h[1] = lh[kp + 1][nl];
        size_t obase = (size_t)tile * TSZ * TSZ + (size_t)(n0 + nl) * TSZ + k0 + kp;
        *(uint32_t*)(wq_t + obase) = a.u;
        *(uint32_t*)(h_t + obase)  = b.u;
    }
}

// ---------------- fused GEMM: per (tile, mb, nb) block computes BOTH ----------
//   P = x_tile @ wq^T  (stats only)   and   Q = x_tile @ h^T (stats + store)
// A staged once per K-step; 32 MFMA per barrier.
DI void gl16(const void* g, void* l) {
    auto gp = reinterpret_cast<const uint32_t __attribute__((address_space(1)))*>(
        reinterpret_cast<uintptr_t>(g));
    auto lp = reinterpret_cast<uint32_t __attribute__((address_space(3)))*>(
        reinterpret_cast<uintptr_t>(l));
    __builtin_amdgcn_global_load_lds(gp, lp, 16, 0, 0);
}

__global__ __launch_bounds__(256, 2)
void gemm_fused(const f16* __restrict__ A, const f16* __restrict__ B1,
                const f16* __restrict__ B2, f16* __restrict__ Qout,
                float* __restrict__ pmx, float* __restrict__ pmn, float* __restrict__ psm,
                float* __restrict__ qmx, float* __restrict__ qmn, float* __restrict__ qsm) {
    __shared__ __align__(16) f16 As[2][4096];    // [buf][128 rows][32 k], 16B-slot swizzle
    __shared__ __align__(16) f16 B1s[2][4096];
    __shared__ __align__(16) f16 B2s[2][4096];
    __shared__ float sred[128][2][4];

    int bx = blockIdx.x;
    int tile = bx >> 5, mb = (bx >> 2) & 7, nb = bx & 3;
    int it = tile >> 3;
    int t = threadIdx.x, lane = t & 63, w = t >> 6;
    int wr = w >> 1, wc = w & 1;

    const f16* Ab  = A  + (size_t)(mb * 128) * NF + it * TSZ;
    const f16* B1b = B1 + ((size_t)tile * TSZ + nb * 128) * TSZ;
    const f16* B2b = B2 + ((size_t)tile * TSZ + nb * 128) * TSZ;

    // staging: 512 16B chunks per matrix; thread stages chunks t and t+256.
    // chunk l -> LDS halfs [8l,8l+8); source k-slot pre-swizzled:
    // slot -> k = (slot ^ ((row>>1)&3))*8
    int l1 = t, l2 = t + 256;
    int r1 = l1 >> 2, k1 = ((l1 & 3) ^ ((r1 >> 1) & 3)) * 8;
    int r2 = l2 >> 2, k2 = ((l2 & 3) ^ ((r2 >> 1) & 3)) * 8;
    const f16* a1  = Ab  + (size_t)r1 * NF  + k1;
    const f16* a2  = Ab  + (size_t)r2 * NF  + k2;
    const f16* b11 = B1b + (size_t)r1 * TSZ + k1;
    const f16* b12 = B1b + (size_t)r2 * TSZ + k2;
    const f16* b21 = B2b + (size_t)r1 * TSZ + k1;
    const f16* b22 = B2b + (size_t)r2 * TSZ + k2;

    f32x4 accP[4][4] = {};
    f32x4 accQ[4][4] = {};

    gl16(a1,  &As[0][w * 512]);  gl16(a2,  &As[0][2048 + w * 512]);
    gl16(b11, &B1s[0][w * 512]); gl16(b12, &B1s[0][2048 + w * 512]);
    gl16(b21, &B2s[0][w * 512]); gl16(b22, &B2s[0][2048 + w * 512]);
    a1 += 32; a2 += 32; b11 += 32; b12 += 32; b21 += 32; b22 += 32;
    __syncthreads();

    int rA = wr * 64 + (lane & 15);
    int rB = wc * 64 + (lane & 15);
    int sl = lane >> 4;

    for (int kt = 0; kt < 16; ++kt) {
        int cur = kt & 1, nxt = cur ^ 1;
        if (kt < 15) {
            gl16(a1,  &As[nxt][w * 512]);  gl16(a2,  &As[nxt][2048 + w * 512]);
            gl16(b11, &B1s[nxt][w * 512]); gl16(b12, &B1s[nxt][2048 + w * 512]);
            gl16(b21, &B2s[nxt][w * 512]); gl16(b22, &B2s[nxt][2048 + w * 512]);
            a1 += 32; a2 += 32; b11 += 32; b12 += 32; b21 += 32; b22 += 32;
        }
        half8 af[4], bf1[4], bf2[4];
#pragma unroll
        for (int m = 0; m < 4; ++m) {
            int row = rA + m * 16;
            af[m] = *(const half8*)&As[cur][row * 32 + ((sl ^ ((row >> 1) & 3)) << 3)];
        }
#pragma unroll
        for (int n = 0; n < 4; ++n) {
            int row = rB + n * 16;
            int o = row * 32 + ((sl ^ ((row >> 1) & 3)) << 3);
            bf1[n] = *(const half8*)&B1s[cur][o];
            bf2[n] = *(const half8*)&B2s[cur][o];
        }
#pragma unroll
        for (int m = 0; m < 4; ++m)
#pragma unroll
            for (int n = 0; n < 4; ++n) {
                accP[m][n] = __builtin_amdgcn_mfma_f32_16x16x32_f16(af[m], bf1[n], accP[m][n], 0, 0, 0);
                accQ[m][n] = __builtin_amdgcn_mfma_f32_16x16x32_f16(af[m], bf2[n], accQ[m][n], 0, 0, 0);
            }
        __syncthreads();
    }

    // ---- stats epilogue: per-row max/min/sum over this block's 128 cols ----
#define ROW_STATS(ACC, DMX, DMN, DSM)                                          \
    {                                                                          \
        _Pragma("unroll")                                                      \
        for (int m = 0; m < 4; ++m) {                                          \
            _Pragma("unroll")                                                  \
            for (int r = 0; r < 4; ++r) {                                      \
                float mx = -3.4e38f, mn = 3.4e38f, sm = 0.f;                   \
                _Pragma("unroll")                                              \
                for (int n = 0; n < 4; ++n) {                                  \
                    float v = ACC[m][n][r];                                    \
                    mx = fmaxf(mx, v); mn = fminf(mn, v); sm += v;             \
                }                                                              \
                _Pragma("unroll")                                              \
                for (int d = 1; d < 16; d <<= 1) {                             \
                    mx = fmaxf(mx, __shfl_xor(mx, d));                         \
                    mn = fminf(mn, __shfl_xor(mn, d));                         \
                    sm += __shfl_xor(sm, d);                                   \
                }                                                              \
                if ((lane & 15) == 0) {                                        \
                    int row = wr * 64 + m * 16 + (lane >> 4) * 4 + r;          \
                    sred[row][wc][0] = mx; sred[row][wc][1] = mn;              \
                    sred[row][wc][2] = sm;                                     \
                }                                                              \
            }                                                                  \
        }                                                                      \
        __syncthreads();                                                       \
        if (t < 128) {                                                         \
            float mx = fmaxf(sred[t][0][0], sred[t][1][0]);                    \
            float mn = fminf(sred[t][0][1], sred[t][1][1]);                    \
            float sm = sred[t][0][2] + sred[t][1][2];                          \
            size_t idx = ((size_t)tile * 1024 + mb * 128 + t) * 4 + nb;        \
            DMX[idx] = mx; DMN[idx] = mn; DSM[idx] = sm;                       \
        }                                                                      \
        __syncthreads();                                                       \
    }

    ROW_STATS(accP, pmx, pmn, psm)
    ROW_STATS(accQ, qmx, qmn, qsm)
#undef ROW_STATS

    // ---- store Q (f16) ----
    size_t base = ((size_t)tile * 1024 + mb * 128) * 512 + nb * 128;
#pragma unroll
    for (int m = 0; m < 4; ++m) {
        int row0 = wr * 64 + m * 16 + (lane >> 4) * 4;
#pragma unroll
        for (int n = 0; n < 4; ++n) {
            int col = wc * 64 + n * 16 + (lane & 15);
#pragma unroll
            for (int r = 0; r < 4; ++r)
                Qout[base + (size_t)(row0 + r) * 512 + col] = (f16)accQ[m][n][r];
        }
    }
}

// ---------------- K5: fold partials -> per-(tile,row) alpha/beta ----------------
__global__ void alphabeta(const float* __restrict__ pmx, const float* __restrict__ pmn,
                          const float* __restrict__ psm,
                          const float* __restrict__ qmx, const float* __restrict__ qmn,
                          const float* __restrict__ qsm,
                          const float* __restrict__ wmin_, const float* __restrict__ wmax_,
                          float* __restrict__ alpha, float* __restrict__ beta) {
    int i = blockIdx.x * 256 + threadIdx.x;          // 64 tiles * 1024 rows
    int tile = i >> 10;
    float s = GRANGE / (wmax_[tile] - wmin_[tile] + 1e-12f);
    size_t p = (size_t)i * 4;
    float pmax = fmaxf(fmaxf(pmx[p], pmx[p+1]), fmaxf(pmx[p+2], pmx[p+3]));
    float pmin = fminf(fminf(pmn[p], pmn[p+1]), fminf(pmn[p+2], pmn[p+3]));
    float psum = psm[p] + psm[p+1] + psm[p+2] + psm[p+3];
    float qmax = fmaxf(fmaxf(qmx[p], qmx[p+1]), fmaxf(qmx[p+2], qmx[p+3]));
    float qmin = fminf(fminf(qmn[p], qmn[p+1]), fminf(qmn[p+2], qmn[p+3]));
    float qsum = qsm[p] + qsm[p+1] + qsm[p+2] + qsm[p+3];
    float coeff = (s * (pmax - pmin)) / (s * (qmax - qmin) + 1e-8f);
    float meanP = psum * (1.0f / 512.0f);
    float meanQ = qsum * (1.0f / 512.0f);
    alpha[i] = coeff;
    beta[i]  = meanP - coeff * meanQ;    // out_tile = alpha*Q + beta  (per row)
}

// ---------------- K6: streaming combine ----------------
__global__ __launch_bounds__(256)
void combine(const f16* __restrict__ Q,
             const float* __restrict__ alpha, const float* __restrict__ beta,
             const float* __restrict__ bias, float* __restrict__ out) {
    int bid = blockIdx.x;
    int jt = bid & 7, b = bid >> 3;
    int t = threadIdx.x;
    float o0 = 0.f, o1 = 0.f, bsum = 0.f;
#pragma unroll
    for (int i = 0; i < 8; ++i) {
        int tile = i * 8 + jt;
        int ab = tile * 1024 + b;
        float a = alpha[ab];
        bsum += beta[ab];
        union { uint32_t u; f16 h[2]; } q2;
        q2.u = ((const uint32_t*)(Q + ((size_t)tile * 1024 + b) * 512))[t];
        o0 = fmaf(a, (float)q2.h[0], o0);
        o1 = fmaf(a, (float)q2.h[1], o1);
    }
    float2 bv = ((const float2*)(bias + jt * 512))[t];
    float2 ov; ov.x = o0 + bsum + bv.x; ov.y = o1 + bsum + bv.y;
    ((float2*)(out + (size_t)b * 4096))[jt * 256 + t] = ov;
}

extern "C" void kernel_launch(void* const* d_in, const int* in_sizes, int n_in,
                              void* d_out, int out_size, void* d_ws, size_t ws_size,
                              hipStream_t stream) {
    const float* x    = (const float*)d_in[0];
    const float* wt   = (const float*)d_in[1];
    const float* bias = (const float*)d_in[2];
    float* out = (float*)d_out;
    char* ws = (char*)d_ws;

    float* wmin = (float*)ws;                  // 64 f32
    float* wmax = (float*)(ws + 256);          // 64 f32
    float* pmin1 = (float*)(ws + 512);         // 1024 f32 stage-1 partials
    float* pmax1 = (float*)(ws + 512 + 4096);  // 1024 f32
    size_t off = 512 + 8192;
    f16* xh   = (f16*)(ws + off); off += (size_t)1024 * 4096 * 2;       //   8 MB
    f16* wq_t = (f16*)(ws + off); off += (size_t)4096 * 4096 * 2;       //  32 MB
    f16* h_t  = (f16*)(ws + off); off += (size_t)4096 * 4096 * 2;       //  32 MB
    float* pmx = (float*)(ws + off); off += (size_t)64 * 1024 * 4 * 4;  //   1 MB
    float* pmn = (float*)(ws + off); off += (size_t)64 * 1024 * 4 * 4;
    float* psm = (float*)(ws + off); off += (size_t)64 * 1024 * 4 * 4;
    float* qmx = (float*)(ws + off); off += (size_t)64 * 1024 * 4 * 4;
    float* qmn = (float*)(ws + off); off += (size_t)64 * 1024 * 4 * 4;
    float* qsm = (float*)(ws + off); off += (size_t)64 * 1024 * 4 * 4;
    float* alpha = (float*)(ws + off); off += (size_t)64 * 1024 * 4;    // 256 KB
    float* beta  = (float*)(ws + off); off += (size_t)64 * 1024 * 4;
    f16* Q    = (f16*)(ws + off);                                       //  64 MB

    convert_x   <<<4096, 256,  0, stream>>>(x, xh);
    tile_minmax1<<<1024, 256,  0, stream>>>(wt, pmin1, pmax1);
    tile_minmax2<<<1,    1024, 0, stream>>>(pmin1, pmax1, wmin, wmax);
    transform_w <<<4096, 256,  0, stream>>>(wt, wmin, wmax, wq_t, h_t);
    gemm_fused  <<<2048, 256,  0, stream>>>(xh, wq_t, h_t, Q,
                                            pmx, pmn, psm, qmx, qmn, qsm);
    alphabeta   <<<256,  256,  0, stream>>>(pmx, pmn, psm, qmx, qmn, qsm,
                                            wmin, wmax, alpha, beta);
    combine     <<<8192, 256,  0, stream>>>(Q, alpha, beta, bias, out);
}